// Round 1
// 775.072 us; speedup vs baseline: 1.0233x; 1.0233x over previous
//
#include <hip/hip_runtime.h>
#include <hip/hip_bf16.h>

#define V_ 262144
#define B_ 4
#define C_ 16
#define F_ 64
#define K_ 100
#define CAP_ 8192
#define SEG_ 8   // emb row segments in k_sums

// ---- ws layout (bytes) ----
#define OFF_WEIGHTS 0
#define OFF_LABELS  4194304
#define OFF_ZERO    5242880
#define OFF_HIST    5242880
#define OFF_CNT     5275648
#define OFF_SUMS    5275712
#define OFF_CCNT    5279808
#define ZERO_BYTES  36944
#define OFF_THRESH  5279824
#define OFF_CVAL    5279840
#define OFF_CIDX    5410912

// K1: weights = prod_c proba; labels = argmax_c y (one-hot => the single hot c);
// class counts; topk histogram. Block = 512 threads over a 4096-voxel contiguous
// span (16 KB contiguous run per c-row vs 4 KB before). y[c=0] never read:
// labels default 0. grid (V/4096, B).
__global__ __launch_bounds__(512) void k_stream(const float* __restrict__ proba,
                                                const float* __restrict__ y,
                                                float* __restrict__ weights,
                                                unsigned char* __restrict__ labels,
                                                int* __restrict__ hist,
                                                int* __restrict__ cnt)
{
    const int b = blockIdx.y;
    const int tid = threadIdx.x;
    const int v0q = blockIdx.x * 1024;      // float4 index of block base (4096 voxels)

    __shared__ int lhist[2048];
    __shared__ int lcnt[16];
    for (int i = tid; i < 2048; i += 512) lhist[i] = 0;
    if (tid < 16) lcnt[tid] = 0;
    __syncthreads();

    const float4* pb = (const float4*)(proba + ((size_t)b * C_) * V_) + v0q + tid;
    const float4* yb = (const float4*)(y     + ((size_t)b * C_) * V_) + v0q + tid;
    const int stride4 = V_ >> 2;            // float4 stride between c-rows

    // c = 0: product init; label stays 0 (one-hot)
    float4 w0 = pb[0], w1 = pb[512];
    int4 l0 = make_int4(0, 0, 0, 0), l1 = make_int4(0, 0, 0, 0);

    #pragma unroll 4
    for (int c = 1; c < C_; c++) {
        float4 p0 = pb[c * stride4],       p1 = pb[c * stride4 + 512];
        float4 q0 = yb[c * stride4],       q1 = yb[c * stride4 + 512];
        w0.x *= p0.x; w0.y *= p0.y; w0.z *= p0.z; w0.w *= p0.w;
        w1.x *= p1.x; w1.y *= p1.y; w1.z *= p1.z; w1.w *= p1.w;
        if (q0.x > 0.f) l0.x = c;
        if (q0.y > 0.f) l0.y = c;
        if (q0.z > 0.f) l0.z = c;
        if (q0.w > 0.f) l0.w = c;
        if (q1.x > 0.f) l1.x = c;
        if (q1.y > 0.f) l1.y = c;
        if (q1.z > 0.f) l1.z = c;
        if (q1.w > 0.f) l1.w = c;
    }

    float4* wout = (float4*)(weights + (size_t)b * V_) + v0q + tid;
    wout[0] = w0; wout[512] = w1;
    uchar4* lout = (uchar4*)(labels + (size_t)b * V_) + v0q + tid;
    lout[0]   = make_uchar4((unsigned char)l0.x, (unsigned char)l0.y,
                            (unsigned char)l0.z, (unsigned char)l0.w);
    lout[512] = make_uchar4((unsigned char)l1.x, (unsigned char)l1.y,
                            (unsigned char)l1.z, (unsigned char)l1.w);

    float wv[8] = {w0.x, w0.y, w0.z, w0.w, w1.x, w1.y, w1.z, w1.w};
    int   lv[8] = {l0.x, l0.y, l0.z, l0.w, l1.x, l1.y, l1.z, l1.w};
    #pragma unroll
    for (int j = 0; j < 8; j++) {
        atomicAdd(&lcnt[lv[j]], 1);
        atomicAdd(&lhist[__float_as_uint(wv[j]) >> 21], 1);
    }
    __syncthreads();
    if (tid < 16) atomicAdd(&cnt[tid], lcnt[tid]);
    for (int i = tid; i < 2048; i += 512)
        if (lhist[i]) atomicAdd(&hist[b * 2048 + i], lhist[i]);
}

// K2 REWRITE: sums[c][f] = sum_v emb[b][f][v] * [label==c].
// One block per (seg, f, b): contiguous 128 KB stream of one emb row + 32 KB
// label slice (L2-hit for 63 of 64 readers). Per-THREAD private LDS
// accumulators acc[tid*17 + c]: zero cross-thread contention, stride 17
// coprime with 32 banks. 1 LDS atomic per element << memory floor.
__global__ __launch_bounds__(256) void k_sums(const float* __restrict__ emb,
                                              const unsigned char* __restrict__ labels,
                                              float* __restrict__ sums)
{
    __shared__ float acc[256 * 17];
    __shared__ float part[256];
    const int tid = threadIdx.x;
    float* my = &acc[tid * 17];
    #pragma unroll
    for (int c = 0; c < 16; c++) my[c] = 0.f;

    const int seg = blockIdx.x;             // 0..SEG_-1
    const int f   = blockIdx.y;             // 0..63
    const int b   = blockIdx.z;             // 0..3
    const int vlen = V_ / SEG_;             // 32768 voxels

    const float4* src = (const float4*)(emb + (((size_t)b << 6) + f) * V_
                                        + (size_t)seg * vlen);
    const unsigned int* lb = (const unsigned int*)(labels + (size_t)b * V_
                                                   + (size_t)seg * vlen);

    // vlen / (256 threads * 4 voxels) = 32 iterations, fully coalesced
    for (int it = 0; it < vlen / 1024; it++) {
        const int i4 = it * 256 + tid;
        float4 vals = src[i4];
        unsigned lu = lb[i4];
        atomicAdd(&my[lu & 0xff], vals.x);
        atomicAdd(&my[(lu >> 8) & 0xff], vals.y);
        atomicAdd(&my[(lu >> 16) & 0xff], vals.z);
        atomicAdd(&my[lu >> 24], vals.w);
    }
    __syncthreads();

    // reduce 256x16 -> 16: stage 1: thread t sums class (t&15) over 16 rows
    {
        const int c = tid & 15, r0 = (tid >> 4) << 4;
        float s = 0.f;
        #pragma unroll
        for (int i = 0; i < 16; i++) s += acc[(r0 + i) * 17 + c];
        part[tid] = s;
    }
    __syncthreads();
    if (tid < 16) {
        float s = 0.f;
        #pragma unroll
        for (int j = 0; j < 16; j++) s += part[j * 16 + tid];
        atomicAdd(&sums[(tid << 6) + f], s);
    }
}

// K3: per-batch suffix scan of 2048-bin histogram -> threshold bin T.
__global__ __launch_bounds__(256) void k_scan(const int* __restrict__ hist,
                                              int* __restrict__ thresh)
{
    const int b = blockIdx.x, tid = threadIdx.x;
    __shared__ int part[256];
    __shared__ int suf[257];
    const int* h = hist + b * 2048;
    int loc[8]; int s = 0;
    for (int i = 0; i < 8; i++) { loc[i] = h[tid * 8 + i]; s += loc[i]; }
    part[tid] = s;
    __syncthreads();
    if (tid == 0) {
        suf[256] = 0;
        for (int t = 255; t >= 0; t--) suf[t] = suf[t + 1] + part[t];
    }
    __syncthreads();
    int cg[9];
    cg[8] = suf[tid + 1];
    for (int i = 7; i >= 0; i--) cg[i] = cg[i + 1] + loc[i];
    for (int i = 0; i < 8; i++)
        if (cg[i] >= K_ && cg[i + 1] < K_) thresh[b] = tid * 8 + i;
}

// K4: collect candidates with bin >= T into per-batch buffers.
__global__ __launch_bounds__(256) void k_collect(const float* __restrict__ weights,
                                                 const int* __restrict__ thresh,
                                                 int* __restrict__ ccnt,
                                                 float* __restrict__ cval,
                                                 int* __restrict__ cidx)
{
    const int b = blockIdx.y;
    const int v = (blockIdx.x * 256 + threadIdx.x) * 4;
    const unsigned T = (unsigned)thresh[b];
    float4 w = *(const float4*)(weights + (size_t)b * V_ + v);
    float wv[4] = {w.x, w.y, w.z, w.w};
    for (int j = 0; j < 4; j++) {
        unsigned bits = __float_as_uint(wv[j]);
        if ((bits >> 21) >= T) {
            int p = atomicAdd(&ccnt[b], 1);
            if (p < CAP_) {
                cval[b * CAP_ + p] = wv[j];
                cidx[b * CAP_ + p] = v + j;
            }
        }
    }
}

// K5: exact top-K select, gather he/hec, build avg, pairwise contrastive loss.
__global__ __launch_bounds__(256) void k_final(const float* __restrict__ emb,
                                               const unsigned char* __restrict__ labels,
                                               const float* __restrict__ sums,
                                               const int* __restrict__ cnt,
                                               const int* __restrict__ ccnt,
                                               const float* __restrict__ cval,
                                               const int* __restrict__ cidx,
                                               float* __restrict__ out)
{
    const int b = blockIdx.x, tid = threadIdx.x;
    __shared__ float avg[1024];
    __shared__ float ec[K_ * 64];
    __shared__ float Ssum[K_ * 64];
    __shared__ float lsum[K_];
    __shared__ int selIdx[K_];
    __shared__ int selLab[K_];
    __shared__ int nk[16];
    __shared__ int lists[16 * K_];
    __shared__ int ofs[17];
    __shared__ float red[256];

    for (int i = tid; i < 1024; i += 256) {
        int c = i >> 6;
        float cn = (float)cnt[c];
        avg[i] = (cn > 0.f) ? 0.9f * sums[i] / fmaxf(cn, 1.f) : 0.f;
    }
    if (tid < K_) { lsum[tid] = 0.f; selIdx[tid] = 0; }
    if (tid < 16) nk[tid] = 0;

    int M = ccnt[b]; if (M > CAP_) M = CAP_;
    const float* cv = cval + b * CAP_;
    const int*   ci = cidx + b * CAP_;
    for (int i = tid; i < M; i += 256) {
        float v = cv[i]; int id = ci[i];
        int rank = 0;
        for (int j = 0; j < M; j++) {
            float vj = cv[j];
            rank += (vj > v) || (vj == v && ci[j] < id);
        }
        if (rank < K_) selIdx[rank] = id;
    }
    __syncthreads();
    for (int i = tid; i < K_; i += 256) selLab[i] = labels[(size_t)b * V_ + selIdx[i]];
    __syncthreads();
    if (tid == 0) {
        for (int i = 0; i < K_; i++) { int c = selLab[i]; lists[c * K_ + nk[c]] = i; nk[c]++; }
        int o = 0;
        for (int c = 0; c < 16; c++) { ofs[c] = o; o += nk[c] * nk[c]; }
        ofs[16] = o;
    }
    __syncthreads();

    for (int e = tid; e < K_ * 64; e += 256) {
        int k = e >> 6, f = e & 63;
        float h = emb[(((size_t)b << 6) + f) * V_ + selIdx[k]];
        int lab = selLab[k];
        float s = 0.f, ev = 0.f, lvv = 0.f;
        for (int c = 0; c < 16; c++) {
            float l = h * avg[(c << 6) + f] / 0.1f;
            float x = expf(l);
            s += x;
            if (c == lab) { ev = x; lvv = l; }
        }
        ec[e] = ev; Ssum[e] = s;
        atomicAdd(&lsum[k], lvv);
    }
    __syncthreads();

    const int P = ofs[16];
    float accv = 0.f;
    for (int p = tid; p < P; p += 256) {
        int c = 0;
        while (p >= ofs[c + 1]) c++;
        int loc = p - ofs[c];
        int n = nk[c];
        int i = lists[c * K_ + loc / n];
        int j = lists[c * K_ + loc % n];
        const float* eci = &ec[i << 6];
        const float* ecj = &ec[j << 6];
        const float* sj  = &Ssum[j << 6];
        float s = 0.f;
        for (int f = 0; f < 64; f++) s += logf(eci[f] + sj[f] - ecj[f]);
        accv += s / ((float)n * (float)n * 64.f);
    }
    for (int i2 = tid; i2 < K_; i2 += 256) {
        int c = selLab[i2];
        accv -= lsum[i2] / ((float)nk[c] * 64.f);
    }
    red[tid] = accv;
    __syncthreads();
    for (int s2 = 128; s2 > 0; s2 >>= 1) {
        if (tid < s2) red[tid] += red[tid + s2];
        __syncthreads();
    }
    if (tid == 0) atomicAdd(out, -red[0] / (float)B_);
}

extern "C" void kernel_launch(void* const* d_in, const int* in_sizes, int n_in,
                              void* d_out, int out_size, void* d_ws, size_t ws_size,
                              hipStream_t stream) {
    const float* proba = (const float*)d_in[0];
    const float* y     = (const float*)d_in[1];
    const float* emb   = (const float*)d_in[2];
    char* ws = (char*)d_ws;

    float* weights        = (float*)(ws + OFF_WEIGHTS);
    unsigned char* labels = (unsigned char*)(ws + OFF_LABELS);
    int* hist             = (int*)(ws + OFF_HIST);
    int* cnt              = (int*)(ws + OFF_CNT);
    float* sums           = (float*)(ws + OFF_SUMS);
    int* ccnt             = (int*)(ws + OFF_CCNT);
    int* thresh           = (int*)(ws + OFF_THRESH);
    float* cval           = (float*)(ws + OFF_CVAL);
    int* cidx             = (int*)(ws + OFF_CIDX);
    float* out            = (float*)d_out;

    hipMemsetAsync(ws + OFF_ZERO, 0, ZERO_BYTES, stream);
    hipMemsetAsync(out, 0, sizeof(float), stream);

    k_stream<<<dim3(V_ / 4096, B_), 512, 0, stream>>>(proba, y, weights, labels, hist, cnt);
    k_sums<<<dim3(SEG_, F_, B_), 256, 0, stream>>>(emb, labels, sums);
    k_scan<<<B_, 256, 0, stream>>>(hist, thresh);
    k_collect<<<dim3(V_ / 1024, B_), 256, 0, stream>>>(weights, thresh, ccnt, cval, cidx);
    k_final<<<B_, 256, 0, stream>>>(emb, labels, sums, cnt, ccnt, cval, cidx, out);
}